// Round 6
// baseline (348.161 us; speedup 1.0000x reference)
//
#include <hip/hip_runtime.h>
#include <hip/hip_bf16.h>
#include <stdint.h>

#define HID 512
#define NACT 64
#define NAG 8
#define NR 16384            // 2048 * 8 rows
#define MAXT1 136           // 128-row tiles (fc4)
#define MAXT2 72            // 256-row tiles (fc1-3)

typedef __bf16 bf16_t;
typedef __bf16 bf16x4 __attribute__((ext_vector_type(4)));
typedef __bf16 bf16x8 __attribute__((ext_vector_type(8)));
typedef float  f32x16 __attribute__((ext_vector_type(16)));

#define MFMA32(a,b,c) __builtin_amdgcn_mfma_f32_32x32x16_bf16((a),(b),(c),0,0,0)

// ---------------- workspace layout (bytes) ----------------
#define OFF_META 0
#define OFF_PERM 4096
#define OFF_WM1  (128*1024)
#define OFF_WM2  (OFF_WM1 + NAG*HID*HID*2)
#define OFF_WM3  (OFF_WM2 + NAG*HID*HID*2)
#define OFF_WM4  (OFF_WM3 + NAG*HID*HID*2)
#define OFF_WIH  (OFF_WM4 + NAG*NACT*HID*2)
#define OFF_WHH  (OFF_WIH + 3*HID*HID*2)
#define OFF_XS   (OFF_WHH + 3*HID*HID*2)        // gathered bf16 inputs (sorted); later: h
#define OFF_HS   (OFF_XS + (size_t)NR*HID*2)    // gathered bf16 hidden (sorted); later: q3
#define OFF_B1   (OFF_HS + (size_t)NR*HID*2)    // x1; later: q2

// ---------------- helpers ----------------
__device__ inline void load_lds16(const void* g, void* l) {
  __builtin_amdgcn_global_load_lds((__attribute__((address_space(1))) void*)g,
                                   (__attribute__((address_space(3))) void*)l,
                                   16, 0, 0);
}
template<int N> __device__ inline void wait_vmcnt() {
  asm volatile("s_waitcnt vmcnt(%0)" :: "n"(N) : "memory");
}
__device__ inline void wait_lgkm0() {
  asm volatile("s_waitcnt lgkmcnt(0)" ::: "memory");
}
#define BAR() __builtin_amdgcn_s_barrier()

// LDS tile: [R rows][64 bf16], 128B/row; 16B slot s of row r holds col-block (s ^ (r&7))
__device__ inline bf16x8 lds_frag(const bf16_t* base, int r, int cb) {
  return *(const bf16x8*)((const char*)base + r*128 + ((cb*16) ^ ((r&7)<<4)));
}
__device__ inline void store8bf(void* dst, float4 a, float4 b) {
  union { bf16_t h[8]; uint4 u; } p;
  p.h[0]=(bf16_t)a.x; p.h[1]=(bf16_t)a.y; p.h[2]=(bf16_t)a.z; p.h[3]=(bf16_t)a.w;
  p.h[4]=(bf16_t)b.x; p.h[5]=(bf16_t)b.y; p.h[6]=(bf16_t)b.z; p.h[7]=(bf16_t)b.w;
  *(uint4*)dst = p.u;
}
__device__ inline float kmask(float w, float t) {
  float s = 1.f / (1.f + __expf(-t));
  float m = fabsf(w) - s;
  return m > 0.f ? copysignf(m, w) : 0.f;
}
__device__ inline float sigm(float x) { return 1.f / (1.f + __expf(-x)); }
__device__ inline float tanh_f(float x) {
  float e = __expf(2.f * fabsf(x));
  return copysignf(1.f - 2.f/(e + 1.f), x);
}

// ---------------- weight prep ----------------
__global__ void k_prep(const float* __restrict__ f1w, const float* __restrict__ f1t,
                       const float* __restrict__ f2w, const float* __restrict__ f2t,
                       const float* __restrict__ f3w, const float* __restrict__ f3t,
                       const float* __restrict__ f4w, const float* __restrict__ f4t,
                       const float* __restrict__ gih, const float* __restrict__ ghh,
                       bf16_t* __restrict__ wm1, bf16_t* __restrict__ wm2,
                       bf16_t* __restrict__ wm3, bf16_t* __restrict__ wm4,
                       bf16_t* __restrict__ wihb, bf16_t* __restrict__ whhb,
                       int* __restrict__ meta)
{
  const int tid = threadIdx.x;
  if (blockIdx.x == 0 && tid < 32) meta[tid] = 0;
  long v = (long)blockIdx.x * 256 + tid;
  const long VR1 = 524288;
  if (v < 3*VR1) {
    int which = (int)(v / VR1);
    long e = (v - (long)which*VR1) * 4;
    const float* W = which==0 ? f1w : (which==1 ? f2w : f3w);
    const float* T = which==0 ? f1t : (which==1 ? f2t : f3t);
    bf16_t* O = which==0 ? wm1 : (which==1 ? wm2 : wm3);
    long oi = e & (long)(HID*HID - 1);
    float4 w = *(const float4*)(W + oi);
    float4 t = *(const float4*)(T + e);
    bf16x4 o;
    o[0]=(bf16_t)kmask(w.x,t.x); o[1]=(bf16_t)kmask(w.y,t.y);
    o[2]=(bf16_t)kmask(w.z,t.z); o[3]=(bf16_t)kmask(w.w,t.w);
    *(bf16x4*)(O + e) = o;
  } else if (v < 3*VR1 + 65536) {
    long e = (v - 3*VR1) * 4;
    long oi = e & (long)(NACT*HID - 1);
    float4 w = *(const float4*)(f4w + oi);
    float4 t = *(const float4*)(f4t + e);
    bf16x4 o;
    o[0]=(bf16_t)kmask(w.x,t.x); o[1]=(bf16_t)kmask(w.y,t.y);
    o[2]=(bf16_t)kmask(w.z,t.z); o[3]=(bf16_t)kmask(w.w,t.w);
    *(bf16x4*)(wm4 + e) = o;
  } else if (v < 3*VR1 + 65536 + 196608) {
    long e = (v - (3*VR1 + 65536)) * 4;
    float4 x = *(const float4*)(gih + e);
    bf16x4 o; o[0]=(bf16_t)x.x; o[1]=(bf16_t)x.y; o[2]=(bf16_t)x.z; o[3]=(bf16_t)x.w;
    *(bf16x4*)(wihb + e) = o;
  } else if (v < 3*VR1 + 65536 + 2*196608) {
    long e = (v - (3*VR1 + 65536 + 196608)) * 4;
    float4 x = *(const float4*)(ghh + e);
    bf16x4 o; o[0]=(bf16_t)x.x; o[1]=(bf16_t)x.y; o[2]=(bf16_t)x.z; o[3]=(bf16_t)x.w;
    *(bf16x4*)(whhb + e) = o;
  }
}

// ---------------- bucket rows by agent ----------------
__global__ void k_count(const int* __restrict__ ids, int* __restrict__ meta) {
  int n = blockIdx.x*256 + threadIdx.x;
  atomicAdd(&meta[ids[n]], 1);
}

__global__ void k_td(int* __restrict__ meta) {
  int off = 0, nt = 0, nt2 = 0;
  for (int a = 0; a < NAG; ++a) {
    int c = meta[a];
    meta[8+a] = off;
    for (int t = 0; t*128 < c; ++t) {                      // 128-row tiles (fc4)
      meta[32 + nt]  = off + t*128;
      meta[192 + nt] = (c - t*128 < 128) ? (c - t*128) : 128;
      meta[352 + nt] = a;
      ++nt;
    }
    for (int t = 0; t*256 < c; ++t) {                      // 256-row tiles (fc1-3)
      meta[520 + nt2] = off + t*256;
      meta[600 + nt2] = (c - t*256 < 256) ? (c - t*256) : 256;
      meta[680 + nt2] = a;
      ++nt2;
    }
    off += c;
  }
  meta[16] = nt;
  meta[17] = nt2;
}

__global__ void k_scatter(const int* __restrict__ ids, int* __restrict__ meta,
                          int* __restrict__ perm) {
  int n = blockIdx.x*256 + threadIdx.x;
  int a = ids[n];
  int pos = atomicAdd(&meta[8+a], 1);
  perm[pos] = n;
}

// ---------------- gather + fp32->bf16 convert ----------------
__global__ void k_gather(const float* __restrict__ inputs, const float* __restrict__ hidden,
                         const int* __restrict__ perm,
                         bf16_t* __restrict__ xs, bf16_t* __restrict__ hs)
{
  int tid = threadIdx.x;
  int rb = blockIdx.x*4 + (tid>>6);
  int m = rb & (NR-1);
  int src = perm[m];
  const float* sp; bf16_t* op;
  if (rb < NR) { sp = inputs + (size_t)src*HID; op = xs + (size_t)m*HID; }
  else         { sp = hidden + (size_t)src*HID; op = hs + (size_t)m*HID; }
  int c = (tid&63)*8;
  float4 v0 = *(const float4*)(sp + c);
  float4 v1 = *(const float4*)(sp + c + 4);
  store8bf(op + c, v0, v1);
}

// ---------------- fc1-3: BM=256, BN=128, 512 thr, 8 waves (4x2), wave tile 64x64 ----------------
// grid (MAXT2, 4). 1 block/CU (LDS 96KB). Counted vmcnt(6); final iteration peeled w/ vmcnt(0).
__global__ __launch_bounds__(512, 1)
void k_fc512(const bf16_t* __restrict__ a_bf, const bf16_t* __restrict__ wbase,
             const float* __restrict__ bias, bf16_t* __restrict__ out_bf,
             const int* __restrict__ meta)
{
  const int bx = blockIdx.x;
  if (bx >= meta[17]) return;
  const int m0 = meta[520+bx], rows = meta[600+bx], agent = meta[680+bx];
  const int o0 = blockIdx.y * 128;
  const bf16_t* W = wbase + (size_t)agent * HID * HID;

  __shared__ bf16_t lds[2][(256+128)*64];

  const int tid = threadIdx.x, lane = tid & 63, wid = tid >> 6;
  const int wrow = wid & 3, wcol = wid >> 2;     // 4 x 2
  const int gsw = (lane&7) ^ ((lane>>3)&7);
  const int lr8 = lane >> 3;

  f32x16 zero;
  #pragma unroll
  for (int i = 0; i < 16; ++i) zero[i] = 0.f;
  f32x16 acc[2][2];
  acc[0][0]=acc[0][1]=acc[1][0]=acc[1][1]=zero;

  auto stage = [&](int kp, int s) {   // 6 glds/thread: A 4 + B 2
    if (kp >= 8) return;
    const int k0 = kp * 64;
    bf16_t* LA = &lds[s][0];
    bf16_t* LB = &lds[s][256*64];
    #pragma unroll
    for (int i = 0; i < 4; ++i) {
      int c = wid*4 + i;
      int r = c*8 + lr8;
      int rl = r < rows ? r : rows-1;
      load_lds16(a_bf + (size_t)(m0+rl)*HID + k0 + gsw*8, (char*)LA + c*1024);
    }
    #pragma unroll
    for (int i = 0; i < 2; ++i) {
      int c = wid*2 + i;
      int r = c*8 + lr8;
      load_lds16(W + (size_t)(o0+r)*HID + k0 + gsw*8, (char*)LB + c*1024);
    }
  };

  auto compute = [&](int t) {
    const bf16_t* LA = &lds[t&1][0];
    const bf16_t* LB = &lds[t&1][256*64];
    #pragma unroll
    for (int kk = 0; kk < 4; ++kk) {
      const int cbb = kk*2 + (lane>>5);
      bf16x8 af[2], bfv[2];
      #pragma unroll
      for (int fm = 0; fm < 2; ++fm)
        af[fm] = lds_frag(LA, wrow*64 + fm*32 + (lane&31), cbb);
      #pragma unroll
      for (int fn = 0; fn < 2; ++fn)
        bfv[fn] = lds_frag(LB, wcol*64 + fn*32 + (lane&31), cbb);
      wait_lgkm0();
      __builtin_amdgcn_s_setprio(1);
      #pragma unroll
      for (int fn = 0; fn < 2; ++fn)
        #pragma unroll
        for (int fm = 0; fm < 2; ++fm)
          acc[fm][fn] = MFMA32(af[fm], bfv[fn], acc[fm][fn]);
      __builtin_amdgcn_s_setprio(0);
      BAR();
    }
  };

  stage(0, 0); stage(1, 1);
  for (int t = 0; t < 7; ++t) {
    wait_vmcnt<6>(); BAR();
    compute(t);
    stage(t + 2, t & 1);
  }
  wait_vmcnt<0>(); BAR();     // tail drain: stage(7) fully landed
  compute(7);

  // epilogue: relu(acc+b) -> bf16 sorted buf
  #pragma unroll
  for (int fn = 0; fn < 2; ++fn) {
    int col = o0 + wcol*64 + fn*32 + (lane&31);
    float bv = bias[col];
    #pragma unroll
    for (int fm = 0; fm < 2; ++fm) {
      #pragma unroll
      for (int g = 0; g < 16; ++g) {
        int rl = wrow*64 + fm*32 + 4*(lane>>5) + (g&3) + 8*(g>>2);
        if (rl < rows) {
          float y = fmaxf(acc[fm][fn][g] + bv, 0.f);
          out_bf[(size_t)(m0+rl)*HID + col] = (bf16_t)y;
        }
      }
    }
  }
}

// ---------------- GRU: BM=256, BN=64, 512 thr, 8 waves (4x2), grid (64,8) ----------------
// LDS 112KB, 1 block/CU, 16 K-steps (8 X + 8 H), counted vmcnt(7); final step peeled.
__global__ __launch_bounds__(512, 1)
void k_gru(const bf16_t* __restrict__ x1, const bf16_t* __restrict__ hs,
           const float* __restrict__ hidden,
           const bf16_t* __restrict__ wih, const bf16_t* __restrict__ whh,
           const float* __restrict__ bih, const float* __restrict__ bhh,
           bf16_t* __restrict__ hbuf, float* __restrict__ hout,
           const int* __restrict__ perm)
{
  const int m0 = blockIdx.x * 256;
  const int j0 = blockIdx.y * 64;
  const int tid = threadIdx.x, lane = tid & 63, wid = tid >> 6;
  const int wrow = wid & 3, wcol = wid >> 2;     // 4 x 2
  const int gsw = (lane&7) ^ ((lane>>3)&7);
  const int lr8 = lane >> 3;

  __shared__ bf16_t lds[2][(256+192)*64];   // A 256x64 + 3 gate-B 64x64

  f32x16 zero;
  #pragma unroll
  for (int i = 0; i < 16; ++i) zero[i] = 0.f;
  f32x16 ar[2], az[2], an[2], ah[2];
  ar[0]=ar[1]=az[0]=az[1]=an[0]=an[1]=ah[0]=ah[1]=zero;

  auto stage = [&](int kp, int s) {   // 7 glds/thread: A 4 + B 3
    if (kp >= 16) return;
    const bf16_t* A  = (kp < 8) ? x1  : hs;
    const bf16_t* Wg = (kp < 8) ? wih : whh;
    const int k0 = (kp & 7) * 64;
    bf16_t* LA = &lds[s][0];
    bf16_t* LB = &lds[s][256*64];
    #pragma unroll
    for (int i = 0; i < 4; ++i) {
      int c = wid*4 + i;
      int r = c*8 + lr8;
      load_lds16(A + (size_t)(m0+r)*HID + k0 + gsw*8, (char*)LA + c*1024);
    }
    #pragma unroll
    for (int i = 0; i < 3; ++i) {
      int c = wid*3 + i;                // 0..23: rows 0..191 = gate*64 + within
      int r = c*8 + lr8;
      int wr = (r>>6)*HID + j0 + (r&63);
      load_lds16(Wg + (size_t)wr*HID + k0 + gsw*8, (char*)LB + c*1024);
    }
  };

  auto body = [&](int t, f32x16 (&a3)[2]) {
    const bf16_t* LA = &lds[t&1][0];
    const bf16_t* LB = &lds[t&1][256*64];
    #pragma unroll
    for (int kk = 0; kk < 4; ++kk) {
      const int cbb = kk*2 + (lane>>5);
      bf16x8 af0 = lds_frag(LA, wrow*64 +      (lane&31), cbb);
      bf16x8 af1 = lds_frag(LA, wrow*64 + 32 + (lane&31), cbb);
      const int rb = wcol*32 + (lane&31);
      bf16x8 b0 = lds_frag(LB,        rb, cbb);
      bf16x8 b1 = lds_frag(LB + 4096, rb, cbb);
      bf16x8 b2 = lds_frag(LB + 8192, rb, cbb);
      wait_lgkm0();
      __builtin_amdgcn_s_setprio(1);
      ar[0] = MFMA32(af0, b0, ar[0]); ar[1] = MFMA32(af1, b0, ar[1]);
      az[0] = MFMA32(af0, b1, az[0]); az[1] = MFMA32(af1, b1, az[1]);
      a3[0] = MFMA32(af0, b2, a3[0]); a3[1] = MFMA32(af1, b2, a3[1]);
      __builtin_amdgcn_s_setprio(0);
      BAR();
    }
  };

  stage(0, 0); stage(1, 1);
  for (int t = 0; t < 8; ++t) {
    wait_vmcnt<7>(); BAR();
    body(t, an);
    stage(t + 2, t & 1);
  }
  for (int t = 8; t < 15; ++t) {
    wait_vmcnt<7>(); BAR();
    body(t, ah);
    stage(t + 2, t & 1);
  }
  wait_vmcnt<0>(); BAR();     // tail drain: stage(15) fully landed
  body(15, ah);

  // ---- epilogue: gates + blend (h_prev exact fp32) ----
  const int col = j0 + wcol*32 + (lane&31);
  const float b_r  = bih[col]        + bhh[col];
  const float b_z  = bih[512 + col]  + bhh[512 + col];
  const float b_in = bih[1024 + col];
  const float b_hn = bhh[1024 + col];
  #pragma unroll
  for (int fm = 0; fm < 2; ++fm) {
    #pragma unroll
    for (int g = 0; g < 16; ++g) {
      int rl = wrow*64 + fm*32 + 4*(lane>>5) + (g&3) + 8*(g>>2);
      int m = m0 + rl;
      int src = perm[m];
      float hp = hidden[(size_t)src*HID + col];
      float rg = sigm(ar[fm][g] + b_r);
      float zg = sigm(az[fm][g] + b_z);
      float ng = tanh_f(an[fm][g] + b_in + rg*(ah[fm][g] + b_hn));
      float h  = (1.f - zg)*ng + zg*hp;
      hbuf[(size_t)m*HID + col] = (bf16_t)h;
      hout[(size_t)src*HID + col] = h;
    }
  }
}

// ---------------- fc4: BM=128, BN=64, 256 thr ----------------
__global__ __launch_bounds__(256, 2)
void k_fc4(const bf16_t* __restrict__ a_bf, const bf16_t* __restrict__ wbase,
           const float* __restrict__ bias, float* __restrict__ out_f32,
           const int* __restrict__ meta, const int* __restrict__ perm)
{
  const int bx = blockIdx.x;
  if (bx >= meta[16]) return;
  const int m0 = meta[32+bx], rows = meta[192+bx], agent = meta[352+bx];
  const bf16_t* W = wbase + (size_t)agent * NACT * HID;

  __shared__ bf16_t lds[2][(128 + 64)*64];

  const int tid = threadIdx.x, lane = tid & 63, wid = tid >> 6;
  const int wrow = wid & 1, wcol = wid >> 1;
  const int gsw = (lane&7) ^ ((lane>>3)&7);
  const int lr8 = lane >> 3;

  f32x16 zero;
  #pragma unroll
  for (int i = 0; i < 16; ++i) zero[i] = 0.f;
  f32x16 acc[2];
  acc[0]=acc[1]=zero;

  auto stage = [&](int kp, int s) {   // 6 glds/thread: A 4 + B 2
    if (kp >= 8) return;
    const int k0 = kp * 64;
    bf16_t* LA = &lds[s][0];
    bf16_t* LB = &lds[s][128*64];
    #pragma unroll
    for (int i = 0; i < 4; ++i) {
      int c = wid*4 + i;
      int r = c*8 + lr8;
      int rl = r < rows ? r : rows-1;
      load_lds16(a_bf + (size_t)(m0+rl)*HID + k0 + gsw*8, (char*)LA + c*1024);
    }
    #pragma unroll
    for (int i = 0; i < 2; ++i) {
      int c = wid*2 + i;
      int r = c*8 + lr8;
      load_lds16(W + (size_t)r*HID + k0 + gsw*8, (char*)LB + c*1024);
    }
  };

  auto compute = [&](int t) {
    const bf16_t* LA = &lds[t&1][0];
    const bf16_t* LB = &lds[t&1][128*64];
    #pragma unroll
    for (int kk = 0; kk < 4; ++kk) {
      const int cbb = kk*2 + (lane>>5);
      bf16x8 af[2];
      #pragma unroll
      for (int fm = 0; fm < 2; ++fm)
        af[fm] = lds_frag(LA, wrow*64 + fm*32 + (lane&31), cbb);
      bf16x8 bv = lds_frag(LB, wcol*32 + (lane&31), cbb);
      wait_lgkm0();
      __builtin_amdgcn_s_setprio(1);
      acc[0] = MFMA32(af[0], bv, acc[0]);
      acc[1] = MFMA32(af[1], bv, acc[1]);
      __builtin_amdgcn_s_setprio(0);
      BAR();
    }
  };

  stage(0, 0); stage(1, 1);
  for (int t = 0; t < 7; ++t) {
    wait_vmcnt<6>(); BAR();
    compute(t);
    stage(t + 2, t & 1);
  }
  wait_vmcnt<0>(); BAR();     // tail drain
  compute(7);

  int col = wcol*32 + (lane&31);
  float bv = bias[col];
  #pragma unroll
  for (int fm = 0; fm < 2; ++fm) {
    #pragma unroll
    for (int g = 0; g < 16; ++g) {
      int rl = wrow*64 + fm*32 + 4*(lane>>5) + (g&3) + 8*(g>>2);
      if (rl < rows)
        out_f32[(size_t)perm[m0+rl]*NACT + col] = acc[fm][g] + bv;
    }
  }
}

// ---------------- launch ----------------
extern "C" void kernel_launch(void* const* d_in, const int* in_sizes, int n_in,
                              void* d_out, int out_size, void* d_ws, size_t ws_size,
                              hipStream_t stream) {
  const float* inputs  = (const float*)d_in[0];
  const float* hidden  = (const float*)d_in[1];
  const int*   ids     = (const int*)  d_in[2];
  const float* fc1_w   = (const float*)d_in[3];
  const float* fc1_b   = (const float*)d_in[4];
  const float* fc1_t   = (const float*)d_in[5];
  const float* gru_wih = (const float*)d_in[6];
  const float* gru_whh = (const float*)d_in[7];
  const float* gru_bih = (const float*)d_in[8];
  const float* gru_bhh = (const float*)d_in[9];
  const float* fc2_w   = (const float*)d_in[10];
  const float* fc2_b   = (const float*)d_in[11];
  const float* fc2_t   = (const float*)d_in[12];
  const float* fc3_w   = (const float*)d_in[13];
  const float* fc3_b   = (const float*)d_in[14];
  const float* fc3_t   = (const float*)d_in[15];
  const float* fc4_w   = (const float*)d_in[16];
  const float* fc4_b   = (const float*)d_in[17];
  const float* fc4_t   = (const float*)d_in[18];

  char* ws = (char*)d_ws;
  int*    meta = (int*)   (ws + OFF_META);
  int*    perm = (int*)   (ws + OFF_PERM);
  bf16_t* wm1  = (bf16_t*)(ws + OFF_WM1);
  bf16_t* wm2  = (bf16_t*)(ws + OFF_WM2);
  bf16_t* wm3  = (bf16_t*)(ws + OFF_WM3);
  bf16_t* wm4  = (bf16_t*)(ws + OFF_WM4);
  bf16_t* wihb = (bf16_t*)(ws + OFF_WIH);
  bf16_t* whhb = (bf16_t*)(ws + OFF_WHH);
  bf16_t* xs   = (bf16_t*)(ws + OFF_XS);
  bf16_t* hs   = (bf16_t*)(ws + OFF_HS);
  bf16_t* b1   = (bf16_t*)(ws + OFF_B1);

  float* q_out = (float*)d_out;                 // [NR][64]
  float* h_out = q_out + (size_t)NR * NACT;     // [NR][512]

  k_prep<<<7936, 256, 0, stream>>>(fc1_w, fc1_t, fc2_w, fc2_t, fc3_w, fc3_t,
                                   fc4_w, fc4_t, gru_wih, gru_whh,
                                   wm1, wm2, wm3, wm4, wihb, whhb, meta);
  k_count<<<64, 256, 0, stream>>>(ids, meta);
  k_td<<<1, 1, 0, stream>>>(meta);
  k_scatter<<<64, 256, 0, stream>>>(ids, meta, perm);
  k_gather<<<8192, 256, 0, stream>>>(inputs, hidden, perm, xs, hs);

  // fc1: xs -> b1
  k_fc512<<<dim3(MAXT2, 4), 512, 0, stream>>>(xs, wm1, fc1_b, b1, meta);
  // GRU: b1 + hs -> xs (sorted bf16) + h_out (fp32 scattered)
  k_gru<<<dim3(NR/256, 8), 512, 0, stream>>>(b1, hs, hidden, wihb, whhb,
                                             gru_bih, gru_bhh, xs, h_out, perm);
  // fc2: xs -> b1
  k_fc512<<<dim3(MAXT2, 4), 512, 0, stream>>>(xs, wm2, fc2_b, b1, meta);
  // fc3: b1 -> hs
  k_fc512<<<dim3(MAXT2, 4), 512, 0, stream>>>(b1, wm3, fc3_b, hs, meta);
  // fc4: hs -> q_out (fp32, scattered, no relu)
  k_fc4<<<dim3(MAXT1, 1), 256, 0, stream>>>(hs, wm4, fc4_b, q_out, meta, perm);
}

// Round 7
// 324.654 us; speedup vs baseline: 1.0724x; 1.0724x over previous
//
#include <hip/hip_runtime.h>
#include <hip/hip_bf16.h>
#include <stdint.h>

#define HID 512
#define NACT 64
#define NAG 8
#define NR 16384            // 2048 * 8 rows
#define MAXT1 136           // 128-row tiles

typedef __bf16 bf16_t;
typedef __bf16 bf16x4 __attribute__((ext_vector_type(4)));
typedef __bf16 bf16x8 __attribute__((ext_vector_type(8)));
typedef float  f32x16 __attribute__((ext_vector_type(16)));

#define MFMA32(a,b,c) __builtin_amdgcn_mfma_f32_32x32x16_bf16((a),(b),(c),0,0,0)

// ---------------- workspace layout (bytes) ----------------
#define OFF_META 0
#define OFF_PERM 4096
#define OFF_WM1  (128*1024)
#define OFF_WM2  (OFF_WM1 + NAG*HID*HID*2)
#define OFF_WM3  (OFF_WM2 + NAG*HID*HID*2)
#define OFF_WM4  (OFF_WM3 + NAG*HID*HID*2)
#define OFF_WIH  (OFF_WM4 + NAG*NACT*HID*2)
#define OFF_WHH  (OFF_WIH + 3*HID*HID*2)
#define OFF_XS   (OFF_WHH + 3*HID*HID*2)        // gathered bf16 inputs (sorted); later: h
#define OFF_HS   (OFF_XS + (size_t)NR*HID*2)    // gathered bf16 hidden (sorted); later: q3
#define OFF_B1   (OFF_HS + (size_t)NR*HID*2)    // x1; later: q2

// ---------------- helpers ----------------
__device__ inline void load_lds16(const void* g, void* l) {
  __builtin_amdgcn_global_load_lds((__attribute__((address_space(1))) void*)g,
                                   (__attribute__((address_space(3))) void*)l,
                                   16, 0, 0);
}
template<int N> __device__ inline void wait_vmcnt() {
  asm volatile("s_waitcnt vmcnt(%0)" :: "n"(N) : "memory");
}
#define BAR() __builtin_amdgcn_s_barrier()

// LDS tile: [R rows][64 bf16], 128B/row; 16B slot s of row r holds col-block (s ^ (r&7))
__device__ inline bf16x8 lds_frag(const bf16_t* base, int r, int cb) {
  return *(const bf16x8*)((const char*)base + r*128 + ((cb*16) ^ ((r&7)<<4)));
}
__device__ inline void store8bf(void* dst, float4 a, float4 b) {
  union { bf16_t h[8]; uint4 u; } p;
  p.h[0]=(bf16_t)a.x; p.h[1]=(bf16_t)a.y; p.h[2]=(bf16_t)a.z; p.h[3]=(bf16_t)a.w;
  p.h[4]=(bf16_t)b.x; p.h[5]=(bf16_t)b.y; p.h[6]=(bf16_t)b.z; p.h[7]=(bf16_t)b.w;
  *(uint4*)dst = p.u;
}
__device__ inline float kmask(float w, float t) {
  float s = 1.f / (1.f + __expf(-t));
  float m = fabsf(w) - s;
  return m > 0.f ? copysignf(m, w) : 0.f;
}
__device__ inline float sigm(float x) { return 1.f / (1.f + __expf(-x)); }
__device__ inline float tanh_f(float x) {
  float e = __expf(2.f * fabsf(x));
  return copysignf(1.f - 2.f/(e + 1.f), x);
}

// ---------------- weight prep ----------------
__global__ void k_prep(const float* __restrict__ f1w, const float* __restrict__ f1t,
                       const float* __restrict__ f2w, const float* __restrict__ f2t,
                       const float* __restrict__ f3w, const float* __restrict__ f3t,
                       const float* __restrict__ f4w, const float* __restrict__ f4t,
                       const float* __restrict__ gih, const float* __restrict__ ghh,
                       bf16_t* __restrict__ wm1, bf16_t* __restrict__ wm2,
                       bf16_t* __restrict__ wm3, bf16_t* __restrict__ wm4,
                       bf16_t* __restrict__ wihb, bf16_t* __restrict__ whhb,
                       int* __restrict__ meta)
{
  const int tid = threadIdx.x;
  if (blockIdx.x == 0 && tid < 32) meta[tid] = 0;
  long v = (long)blockIdx.x * 256 + tid;
  const long VR1 = 524288;
  if (v < 3*VR1) {
    int which = (int)(v / VR1);
    long e = (v - (long)which*VR1) * 4;
    const float* W = which==0 ? f1w : (which==1 ? f2w : f3w);
    const float* T = which==0 ? f1t : (which==1 ? f2t : f3t);
    bf16_t* O = which==0 ? wm1 : (which==1 ? wm2 : wm3);
    long oi = e & (long)(HID*HID - 1);
    float4 w = *(const float4*)(W + oi);
    float4 t = *(const float4*)(T + e);
    bf16x4 o;
    o[0]=(bf16_t)kmask(w.x,t.x); o[1]=(bf16_t)kmask(w.y,t.y);
    o[2]=(bf16_t)kmask(w.z,t.z); o[3]=(bf16_t)kmask(w.w,t.w);
    *(bf16x4*)(O + e) = o;
  } else if (v < 3*VR1 + 65536) {
    long e = (v - 3*VR1) * 4;
    long oi = e & (long)(NACT*HID - 1);
    float4 w = *(const float4*)(f4w + oi);
    float4 t = *(const float4*)(f4t + e);
    bf16x4 o;
    o[0]=(bf16_t)kmask(w.x,t.x); o[1]=(bf16_t)kmask(w.y,t.y);
    o[2]=(bf16_t)kmask(w.z,t.z); o[3]=(bf16_t)kmask(w.w,t.w);
    *(bf16x4*)(wm4 + e) = o;
  } else if (v < 3*VR1 + 65536 + 196608) {
    long e = (v - (3*VR1 + 65536)) * 4;
    float4 x = *(const float4*)(gih + e);
    bf16x4 o; o[0]=(bf16_t)x.x; o[1]=(bf16_t)x.y; o[2]=(bf16_t)x.z; o[3]=(bf16_t)x.w;
    *(bf16x4*)(wihb + e) = o;
  } else if (v < 3*VR1 + 65536 + 2*196608) {
    long e = (v - (3*VR1 + 65536 + 196608)) * 4;
    float4 x = *(const float4*)(ghh + e);
    bf16x4 o; o[0]=(bf16_t)x.x; o[1]=(bf16_t)x.y; o[2]=(bf16_t)x.z; o[3]=(bf16_t)x.w;
    *(bf16x4*)(whhb + e) = o;
  }
}

// ---------------- bucket rows by agent ----------------
__global__ void k_count(const int* __restrict__ ids, int* __restrict__ meta) {
  int n = blockIdx.x*256 + threadIdx.x;
  atomicAdd(&meta[ids[n]], 1);
}

__global__ void k_td(int* __restrict__ meta) {
  int off = 0, nt = 0;
  for (int a = 0; a < NAG; ++a) {
    int c = meta[a];
    meta[8+a] = off;
    for (int t = 0; t*128 < c; ++t) {
      meta[32 + nt]  = off + t*128;
      meta[192 + nt] = (c - t*128 < 128) ? (c - t*128) : 128;
      meta[352 + nt] = a;
      ++nt;
    }
    off += c;
  }
  meta[16] = nt;
}

__global__ void k_scatter(const int* __restrict__ ids, int* __restrict__ meta,
                          int* __restrict__ perm) {
  int n = blockIdx.x*256 + threadIdx.x;
  int a = ids[n];
  int pos = atomicAdd(&meta[8+a], 1);
  perm[pos] = n;
}

// ---------------- gather + fp32->bf16 convert ----------------
__global__ void k_gather(const float* __restrict__ inputs, const float* __restrict__ hidden,
                         const int* __restrict__ perm,
                         bf16_t* __restrict__ xs, bf16_t* __restrict__ hs)
{
  int tid = threadIdx.x;
  int rb = blockIdx.x*4 + (tid>>6);
  int m = rb & (NR-1);
  int src = perm[m];
  const float* sp; bf16_t* op;
  if (rb < NR) { sp = inputs + (size_t)src*HID; op = xs + (size_t)m*HID; }
  else         { sp = hidden + (size_t)src*HID; op = hs + (size_t)m*HID; }
  int c = (tid&63)*8;
  float4 v0 = *(const float4*)(sp + c);
  float4 v1 = *(const float4*)(sp + c + 4);
  store8bf(op + c, v0, v1);
}

// ---------------- grouped kalei GEMM: BM=128, 4 waves (2x2), read-ahead pipeline ----------------
// 2 barriers/K-step; frag regs double-buffered so ds_reads(kk+1) overlap MFMA(kk).
template<int BN, int OTOT, int OUTMODE>     // BN=128 (fc1-3) or 64 (fc4)
__global__ __launch_bounds__(256, 2)
void k_fc(const bf16_t* __restrict__ a_bf, const bf16_t* __restrict__ wbase,
          const float* __restrict__ bias,
          bf16_t* __restrict__ out_bf, float* __restrict__ out_f32,
          const int* __restrict__ meta, const int* __restrict__ perm)
{
  constexpr int FN  = BN/64;          // B frags per kk (2 or 1)
  constexpr int NLB = BN/32;          // B glds per thread per step
  constexpr int NLD = 4 + NLB;
  const int bx = blockIdx.x;
  if (bx >= meta[16]) return;
  const int m0 = meta[32+bx], rows = meta[192+bx], agent = meta[352+bx];
  const int o0 = blockIdx.y * BN;
  const bf16_t* W = wbase + (size_t)agent * OTOT * HID;

  __shared__ bf16_t lds[2][(128 + BN)*64];

  const int tid = threadIdx.x, lane = tid & 63, wid = tid >> 6;
  const int wrow = wid & 1, wcol = wid >> 1;
  const int gsw = (lane&7) ^ ((lane>>3)&7);
  const int lr8 = lane >> 3;

  f32x16 zero;
  #pragma unroll
  for (int i = 0; i < 16; ++i) zero[i] = 0.f;
  f32x16 acc[2][FN];
  #pragma unroll
  for (int i = 0; i < 2; ++i)
    #pragma unroll
    for (int j = 0; j < FN; ++j) acc[i][j] = zero;

  auto stage = [&](int kp, int s) {
    if (kp >= 8) return;
    const int k0 = kp * 64;
    bf16_t* LA = &lds[s][0];
    bf16_t* LB = &lds[s][128*64];
    #pragma unroll
    for (int i = 0; i < 4; ++i) {
      int c = wid*4 + i;
      int r = c*8 + lr8;
      int rl = r < rows ? r : rows-1;
      load_lds16(a_bf + (size_t)(m0+rl)*HID + k0 + gsw*8, (char*)LA + c*1024);
    }
    #pragma unroll
    for (int i = 0; i < NLB; ++i) {
      int c = wid*NLB + i;
      int r = c*8 + lr8;
      load_lds16(W + (size_t)(o0+r)*HID + k0 + gsw*8, (char*)LB + c*1024);
    }
  };

  auto body = [&](int t) {
    const bf16_t* LA = &lds[t&1][0];
    const bf16_t* LB = &lds[t&1][128*64];
    bf16x8 a0A,a1A,b0A,b1A, a0B,a1B,b0B,b1B;
    auto rd = [&](int kk, bf16x8& a0, bf16x8& a1, bf16x8& b0, bf16x8& b1) {
      const int cbb = kk*2 + (lane>>5);
      a0 = lds_frag(LA, wrow*64 +      (lane&31), cbb);
      a1 = lds_frag(LA, wrow*64 + 32 + (lane&31), cbb);
      b0 = lds_frag(LB, wcol*(BN/2) +      (lane&31), cbb);
      if constexpr (FN == 2)
        b1 = lds_frag(LB, wcol*(BN/2) + 32 + (lane&31), cbb);
    };
    auto mm = [&](bf16x8& a0, bf16x8& a1, bf16x8& b0, bf16x8& b1) {
      __builtin_amdgcn_s_setprio(1);
      acc[0][0] = MFMA32(a0, b0, acc[0][0]);
      acc[1][0] = MFMA32(a1, b0, acc[1][0]);
      if constexpr (FN == 2) {
        acc[0][1] = MFMA32(a0, b1, acc[0][1]);
        acc[1][1] = MFMA32(a1, b1, acc[1][1]);
      }
      __builtin_amdgcn_s_setprio(0);
    };
    rd(0, a0A,a1A,b0A,b1A);
    rd(1, a0B,a1B,b0B,b1B);  mm(a0A,a1A,b0A,b1A);
    rd(2, a0A,a1A,b0A,b1A);  mm(a0B,a1B,b0B,b1B);
    rd(3, a0B,a1B,b0B,b1B);  mm(a0A,a1A,b0A,b1A);
    mm(a0B,a1B,b0B,b1B);
  };

  stage(0, 0); stage(1, 1);
  for (int t = 0; t < 7; ++t) {
    wait_vmcnt<NLD>(); BAR();   // buf[t] staged everywhere
    body(t);
    BAR();                      // all waves done reading buf[t]
    stage(t + 2, t & 1);
  }
  wait_vmcnt<0>(); BAR();       // tail drain
  body(7);

  // epilogue: C layout (32x32): col=lane&31, row=4*(lane>>5)+(g&3)+8*(g>>2)
  #pragma unroll
  for (int fn = 0; fn < FN; ++fn) {
    int col = o0 + wcol*(BN/2) + fn*32 + (lane&31);
    float bv = bias[col];
    #pragma unroll
    for (int fm = 0; fm < 2; ++fm) {
      #pragma unroll
      for (int g = 0; g < 16; ++g) {
        int rl = wrow*64 + fm*32 + 4*(lane>>5) + (g&3) + 8*(g>>2);
        if (rl < rows) {
          float y = acc[fm][fn][g] + bv;
          if constexpr (OUTMODE == 0) {
            y = fmaxf(y, 0.f);
            out_bf[(size_t)(m0+rl)*OTOT + col] = (bf16_t)y;
          } else {
            out_f32[(size_t)perm[m0+rl]*OTOT + col] = y;
          }
        }
      }
    }
  }
}

// ---------------- fused GRU: BM=128, BN=64, 4 waves (2x2), read-ahead pipeline ----------------
// grid (128, 8), 2 blocks/CU (LDS 80KB), 16 K-steps (8 X + 8 H), vmcnt(10) counted.
__global__ __launch_bounds__(256, 2)
void k_gru(const bf16_t* __restrict__ x1, const bf16_t* __restrict__ hs,
           const float* __restrict__ hidden,
           const bf16_t* __restrict__ wih, const bf16_t* __restrict__ whh,
           const float* __restrict__ bih, const float* __restrict__ bhh,
           bf16_t* __restrict__ hbuf, float* __restrict__ hout,
           const int* __restrict__ perm)
{
  const int m0 = blockIdx.x * 128;
  const int j0 = blockIdx.y * 64;
  const int tid = threadIdx.x, lane = tid & 63, wid = tid >> 6;
  const int wrow = wid & 1, wcol = wid >> 1;
  const int gsw = (lane&7) ^ ((lane>>3)&7);
  const int lr8 = lane >> 3;

  __shared__ bf16_t lds[2][(128+192)*64];   // A 128x64 + 3 gate-B 64x64

  f32x16 zero;
  #pragma unroll
  for (int i = 0; i < 16; ++i) zero[i] = 0.f;
  f32x16 ar[2], az[2], an[2], ah[2];
  ar[0]=ar[1]=az[0]=az[1]=an[0]=an[1]=ah[0]=ah[1]=zero;

  auto stage = [&](int kp, int s) {   // 10 glds/thread: A 4 + B 6
    if (kp >= 16) return;
    const bf16_t* A  = (kp < 8) ? x1  : hs;
    const bf16_t* Wg = (kp < 8) ? wih : whh;
    const int k0 = (kp & 7) * 64;
    bf16_t* LA = &lds[s][0];
    bf16_t* LB = &lds[s][128*64];
    #pragma unroll
    for (int i = 0; i < 4; ++i) {
      int c = wid*4 + i;
      int r = c*8 + lr8;
      load_lds16(A + (size_t)(m0+r)*HID + k0 + gsw*8, (char*)LA + c*1024);
    }
    #pragma unroll
    for (int i = 0; i < 6; ++i) {
      int c = wid*6 + i;                // 0..23: rows 0..191 = gate*64 + within
      int r = c*8 + lr8;
      int wr = (r>>6)*HID + j0 + (r&63);
      load_lds16(Wg + (size_t)wr*HID + k0 + gsw*8, (char*)LB + c*1024);
    }
  };

  auto body = [&](int t, f32x16 (&a3)[2]) {
    const bf16_t* LA = &lds[t&1][0];
    const bf16_t* LB = &lds[t&1][128*64];
    bf16x8 a0A,a1A,b0A,b1A,b2A, a0B,a1B,b0B,b1B,b2B;
    auto rd = [&](int kk, bf16x8& a0, bf16x8& a1, bf16x8& b0, bf16x8& b1, bf16x8& b2) {
      const int cbb = kk*2 + (lane>>5);
      a0 = lds_frag(LA, wrow*64 +      (lane&31), cbb);
      a1 = lds_frag(LA, wrow*64 + 32 + (lane&31), cbb);
      const int rb = wcol*32 + (lane&31);
      b0 = lds_frag(LB,        rb, cbb);
      b1 = lds_frag(LB + 4096, rb, cbb);
      b2 = lds_frag(LB + 8192, rb, cbb);
    };
    auto mm = [&](bf16x8& a0, bf16x8& a1, bf16x8& b0, bf16x8& b1, bf16x8& b2) {
      __builtin_amdgcn_s_setprio(1);
      ar[0] = MFMA32(a0, b0, ar[0]); ar[1] = MFMA32(a1, b0, ar[1]);
      az[0] = MFMA32(a0, b1, az[0]); az[1] = MFMA32(a1, b1, az[1]);
      a3[0] = MFMA32(a0, b2, a3[0]); a3[1] = MFMA32(a1, b2, a3[1]);
      __builtin_amdgcn_s_setprio(0);
    };
    rd(0, a0A,a1A,b0A,b1A,b2A);
    rd(1, a0B,a1B,b0B,b1B,b2B);  mm(a0A,a1A,b0A,b1A,b2A);
    rd(2, a0A,a1A,b0A,b1A,b2A);  mm(a0B,a1B,b0B,b1B,b2B);
    rd(3, a0B,a1B,b0B,b1B,b2B);  mm(a0A,a1A,b0A,b1A,b2A);
    mm(a0B,a1B,b0B,b1B,b2B);
  };

  stage(0, 0); stage(1, 1);
  for (int t = 0; t < 8; ++t) {
    wait_vmcnt<10>(); BAR();
    body(t, an);
    BAR();
    stage(t + 2, t & 1);
  }
  for (int t = 8; t < 15; ++t) {
    wait_vmcnt<10>(); BAR();
    body(t, ah);
    BAR();
    stage(t + 2, t & 1);
  }
  wait_vmcnt<0>(); BAR();
  body(15, ah);

  // ---- epilogue: gates + blend (h_prev exact fp32) ----
  const int col = j0 + wcol*32 + (lane&31);
  const float b_r  = bih[col]        + bhh[col];
  const float b_z  = bih[512 + col]  + bhh[512 + col];
  const float b_in = bih[1024 + col];
  const float b_hn = bhh[1024 + col];
  #pragma unroll
  for (int fm = 0; fm < 2; ++fm) {
    #pragma unroll
    for (int g = 0; g < 16; ++g) {
      int rl = wrow*64 + fm*32 + 4*(lane>>5) + (g&3) + 8*(g>>2);
      int m = m0 + rl;
      int src = perm[m];
      float hp = hidden[(size_t)src*HID + col];
      float rg = sigm(ar[fm][g] + b_r);
      float zg = sigm(az[fm][g] + b_z);
      float ng = tanh_f(an[fm][g] + b_in + rg*(ah[fm][g] + b_hn));
      float h  = (1.f - zg)*ng + zg*hp;
      hbuf[(size_t)m*HID + col] = (bf16_t)h;
      hout[(size_t)src*HID + col] = h;
    }
  }
}

// ---------------- launch ----------------
extern "C" void kernel_launch(void* const* d_in, const int* in_sizes, int n_in,
                              void* d_out, int out_size, void* d_ws, size_t ws_size,
                              hipStream_t stream) {
  const float* inputs  = (const float*)d_in[0];
  const float* hidden  = (const float*)d_in[1];
  const int*   ids     = (const int*)  d_in[2];
  const float* fc1_w   = (const float*)d_in[3];
  const float* fc1_b   = (const float*)d_in[4];
  const float* fc1_t   = (const float*)d_in[5];
  const float* gru_wih = (const float*)d_in[6];
  const float* gru_whh = (const float*)d_in[7];
  const float* gru_bih = (const float*)d_in[8];
  const float* gru_bhh = (const float*)d_in[9];
  const float* fc2_w   = (const float*)d_in[10];
  const float* fc2_b   = (const float*)d_in[11];
  const float* fc2_t   = (const float*)d_in[12];
  const float* fc3_w   = (const float*)d_in[13];
  const float* fc3_b   = (const float*)d_in[14];
  const float* fc3_t   = (const float*)d_in[15];
  const float* fc4_w   = (const float*)d_in[16];
  const float* fc4_b   = (const float*)d_in[17];
  const float* fc4_t   = (const float*)d_in[18];

  char* ws = (char*)d_ws;
  int*    meta = (int*)   (ws + OFF_META);
  int*    perm = (int*)   (ws + OFF_PERM);
  bf16_t* wm1  = (bf16_t*)(ws + OFF_WM1);
  bf16_t* wm2  = (bf16_t*)(ws + OFF_WM2);
  bf16_t* wm3  = (bf16_t*)(ws + OFF_WM3);
  bf16_t* wm4  = (bf16_t*)(ws + OFF_WM4);
  bf16_t* wihb = (bf16_t*)(ws + OFF_WIH);
  bf16_t* whhb = (bf16_t*)(ws + OFF_WHH);
  bf16_t* xs   = (bf16_t*)(ws + OFF_XS);
  bf16_t* hs   = (bf16_t*)(ws + OFF_HS);
  bf16_t* b1   = (bf16_t*)(ws + OFF_B1);

  float* q_out = (float*)d_out;                 // [NR][64]
  float* h_out = q_out + (size_t)NR * NACT;     // [NR][512]

  k_prep<<<7936, 256, 0, stream>>>(fc1_w, fc1_t, fc2_w, fc2_t, fc3_w, fc3_t,
                                   fc4_w, fc4_t, gru_wih, gru_whh,
                                   wm1, wm2, wm3, wm4, wihb, whhb, meta);
  k_count<<<64, 256, 0, stream>>>(ids, meta);
  k_td<<<1, 1, 0, stream>>>(meta);
  k_scatter<<<64, 256, 0, stream>>>(ids, meta, perm);
  k_gather<<<8192, 256, 0, stream>>>(inputs, hidden, perm, xs, hs);

  // fc1: xs -> b1
  k_fc<128, HID, 0><<<dim3(MAXT1, 4), 256, 0, stream>>>(
      xs, wm1, fc1_b, b1, nullptr, meta, perm);
  // GRU: b1 + hs -> xs (sorted bf16) + h_out (fp32 scattered)
  k_gru<<<dim3(NR/128, 8), 256, 0, stream>>>(b1, hs, hidden, wihb, whhb,
                                             gru_bih, gru_bhh, xs, h_out, perm);
  // fc2: xs -> b1
  k_fc<128, HID, 0><<<dim3(MAXT1, 4), 256, 0, stream>>>(
      xs, wm2, fc2_b, b1, nullptr, meta, perm);
  // fc3: b1 -> hs
  k_fc<128, HID, 0><<<dim3(MAXT1, 4), 256, 0, stream>>>(
      b1, wm3, fc3_b, hs, nullptr, meta, perm);
  // fc4: hs -> q_out (fp32, scattered, no relu)
  k_fc<64, NACT, 1><<<dim3(MAXT1, 1), 256, 0, stream>>>(
      hs, wm4, fc4_b, nullptr, q_out, meta, perm);
}